// Round 7
// baseline (323.486 us; speedup 1.0000x reference)
//
#include <hip/hip_runtime.h>
#include <hip/hip_bf16.h>
#include <cstddef>

#define NB  4
#define NC  256
#define NN  4096
#define DQK 32
#define MT  32      // query rows per flash block
#define JT  64      // key tile per iteration
#define NIT (NN / JT)
#define PSTR 72     // P row stride in bf16 (144 B rows)

typedef __attribute__((ext_vector_type(8))) short short8;
typedef __attribute__((ext_vector_type(4))) float f32x4;

#define MFMA16(a, b, c) __builtin_amdgcn_mfma_f32_16x16x32_bf16((a), (b), (c), 0, 0, 0)

__device__ inline unsigned pk2bf(float a, float b) {
  __hip_bfloat162 h = __float22bfloat162_rn(make_float2(a, b));
  unsigned u;
  __builtin_memcpy(&u, &h, 4);
  return u;
}

// ---- q/k projections (scalar-weight SGPR-broadcast FMA; r1 structure, bf16 out) ----
__global__ __launch_bounds__(256) void proj_qk_kernel(
    const float* __restrict__ x, const float* __restrict__ Wq,
    const float* __restrict__ bq, const float* __restrict__ Wk,
    const float* __restrict__ bk, __hip_bfloat16* __restrict__ q,
    __hip_bfloat16* __restrict__ kT) {
  const int t = threadIdx.x;
  const int b = blockIdx.y;
  const int n = blockIdx.x * 64 + (t & 63);
  const int g = __builtin_amdgcn_readfirstlane(t >> 6);   // 0,1: q ; 2,3: k
  const float* W    = (g < 2) ? Wq : Wk;
  const float* bias = (g < 2) ? bq : bk;
  const int obase = (g & 1) * 16;

  float acc[16];
#pragma unroll
  for (int i = 0; i < 16; ++i) acc[i] = bias[obase + i];

  const float* xp = x + ((size_t)b * NC) * NN + n;
#pragma unroll 4
  for (int c = 0; c < NC; ++c) {
    float xv = xp[(size_t)c * NN];               // coalesced across lanes
#pragma unroll
    for (int i = 0; i < 16; ++i) acc[i] += W[(obase + i) * NC + c] * xv;
  }
  __hip_bfloat16* dst = ((g < 2) ? q : kT) + ((size_t)b * NN + n) * DQK + obase;
  unsigned p[8];
#pragma unroll
  for (int i = 0; i < 8; ++i) p[i] = pk2bf(acc[2 * i], acc[2 * i + 1]);
  ((uint4*)dst)[0] = make_uint4(p[0], p[1], p[2], p[3]);
  ((uint4*)dst)[1] = make_uint4(p[4], p[5], p[6], p[7]);
}

// ---- v projection: 128 o-rows per block (x read 2x), coalesced bf16 stores ----
__global__ __launch_bounds__(256) void proj_v_kernel(
    const float* __restrict__ x, const float* __restrict__ Wv,
    const float* __restrict__ bv, __hip_bfloat16* __restrict__ v) {
  const int t = threadIdx.x;
  const int b = blockIdx.z;
  const int n = blockIdx.x * 64 + (t & 63);
  const int g = __builtin_amdgcn_readfirstlane(t >> 6);
  const int obase = blockIdx.y * 128 + g * 32;

  float acc[32];
#pragma unroll
  for (int i = 0; i < 32; ++i) acc[i] = bv[obase + i];

  const float* xp = x + ((size_t)b * NC) * NN + n;
#pragma unroll 2
  for (int c = 0; c < NC; ++c) {
    float xv = xp[(size_t)c * NN];
#pragma unroll
    for (int i = 0; i < 32; ++i) acc[i] += Wv[(obase + i) * NC + c] * xv;
  }
#pragma unroll
  for (int i = 0; i < 32; ++i)
    v[((size_t)b * NC + obase + i) * NN + n] = __hip_bfloat16(acc[i]);  // 128B/wave
}

// ---- wave-specialized flash, MT=32: waves 0-1 produce P (QK+softmax),
// ---- waves 2-3 consume (PV, 128 c each), double-buffered P, 1 barrier/iter.
__global__ __launch_bounds__(256, 2) void flash_kernel(
    const __hip_bfloat16* __restrict__ q, const __hip_bfloat16* __restrict__ kt,
    const __hip_bfloat16* __restrict__ v, const float* __restrict__ x,
    const float* __restrict__ gamma, float* __restrict__ out) {
  __shared__ __hip_bfloat16 Ps[2][MT * PSTR];   // 9216 B
  __shared__ float arow[2][MT];
  __shared__ float lrow[MT];

  const int t  = threadIdx.x;
  const int bi = blockIdx.x;
  // XCD swizzle: XCD pair {2b,2b+1} serves batch b -> V slice ~2 MB in L2
  const int b  = (bi & 7) >> 1;
  const int m0 = (((bi & 1) * 64) + (bi >> 3)) * MT;   // 128 m-tiles per batch

  const int w    = __builtin_amdgcn_readfirstlane(t >> 6);   // 0..3
  const int ln   = t & 15;
  const int quad = (t & 63) >> 4;

  const __hip_bfloat16* kb_base = kt + (size_t)b * NN * DQK;
  const __hip_bfloat16* v_base  = v + (size_t)b * NC * NN;

  if (w < 2) {
    // ---------------- producer: rows [m0+w*16, m0+w*16+16) ----------------
    const short8 qa =
        *(const short8*)(q + ((size_t)b * NN + m0 + w * 16 + ln) * DQK + quad * 8);
    float mreg[4], lreg[4];
#pragma unroll
    for (int r = 0; r < 4; ++r) { mreg[r] = -3.0e38f; lreg[r] = 0.f; }

    f32x4 zero4 = {0.f, 0.f, 0.f, 0.f};
    short8 kb[4];
#pragma unroll
    for (int jt = 0; jt < 4; ++jt)
      kb[jt] = *(const short8*)(kb_base + (size_t)(jt * 16 + ln) * DQK + quad * 8);

    for (int it = 0; it < NIT; ++it) {
      f32x4 sf[4];
#pragma unroll
      for (int jt = 0; jt < 4; ++jt) sf[jt] = MFMA16(qa, kb[jt], zero4);

      if (it + 1 < NIT) {
        const int jn = (it + 1) * JT;
#pragma unroll
        for (int jt = 0; jt < 4; ++jt)
          kb[jt] = *(const short8*)(kb_base + (size_t)(jn + jt * 16 + ln) * DQK + quad * 8);
      }

      // wave-local online softmax (rows quad*4+r, cols jt*16+ln)
      float rmax[4];
#pragma unroll
      for (int r = 0; r < 4; ++r)
        rmax[r] = fmaxf(fmaxf(sf[0][r], sf[1][r]), fmaxf(sf[2][r], sf[3][r]));
#pragma unroll
      for (int off = 1; off < 16; off <<= 1)
#pragma unroll
        for (int r = 0; r < 4; ++r)
          rmax[r] = fmaxf(rmax[r], __shfl_xor(rmax[r], off));
      float alpha[4];
#pragma unroll
      for (int r = 0; r < 4; ++r) {
        const float mn = fmaxf(mreg[r], rmax[r]);
        alpha[r] = __expf(mreg[r] - mn);
        mreg[r] = mn;
      }
      float e[4][4], rsum[4];
#pragma unroll
      for (int r = 0; r < 4; ++r) rsum[r] = 0.f;
#pragma unroll
      for (int jt = 0; jt < 4; ++jt)
#pragma unroll
        for (int r = 0; r < 4; ++r) {
          e[jt][r] = __expf(sf[jt][r] - mreg[r]);
          rsum[r] += e[jt][r];
        }
#pragma unroll
      for (int off = 1; off < 16; off <<= 1)
#pragma unroll
        for (int r = 0; r < 4; ++r) rsum[r] += __shfl_xor(rsum[r], off);
#pragma unroll
      for (int r = 0; r < 4; ++r) lreg[r] = lreg[r] * alpha[r] + rsum[r];

      const int buf = it & 1;
#pragma unroll
      for (int jt = 0; jt < 4; ++jt)
#pragma unroll
        for (int r = 0; r < 4; ++r)
          Ps[buf][(w * 16 + quad * 4 + r) * PSTR + jt * 16 + ln] = __hip_bfloat16(e[jt][r]);
      if (ln == 0) {
#pragma unroll
        for (int r = 0; r < 4; ++r) arow[buf][w * 16 + quad * 4 + r] = alpha[r];
      }
      __syncthreads();   // barrier #(it+1)
    }
    if (ln == 0) {
#pragma unroll
      for (int r = 0; r < 4; ++r) lrow[w * 16 + quad * 4 + r] = lreg[r];
    }
    __syncthreads();     // barrier #(NIT+1)
  } else {
    // -------- consumer: channels [c0, c0+128), one iter behind --------
    const int c0 = (w - 2) * 128;
    f32x4 zero4 = {0.f, 0.f, 0.f, 0.f};
    f32x4 acc[8][2];   // rows c = c0+ct*16+quad*4+r, cols m = mt*16+ln
#pragma unroll
    for (int ct = 0; ct < 8; ++ct)
#pragma unroll
      for (int mt = 0; mt < 2; ++mt) acc[ct][mt] = zero4;

    short8 va[8][2];
#pragma unroll
    for (int ct = 0; ct < 8; ++ct)
#pragma unroll
      for (int ks = 0; ks < 2; ++ks)
        va[ct][ks] = *(const short8*)(v_base +
            (size_t)(c0 + ct * 16 + ln) * NN + ks * 32 + quad * 8);
    __syncthreads();   // barrier #1

    for (int it = 1; it < NIT; ++it) {
      const int pbuf = (it - 1) & 1;
      float av[2];
#pragma unroll
      for (int mt = 0; mt < 2; ++mt) av[mt] = arow[pbuf][mt * 16 + ln];
#pragma unroll
      for (int ct = 0; ct < 8; ++ct)
#pragma unroll
        for (int mt = 0; mt < 2; ++mt) acc[ct][mt] *= av[mt];

#pragma unroll
      for (int ks = 0; ks < 2; ++ks) {
        short8 pb[2];
#pragma unroll
        for (int mt = 0; mt < 2; ++mt)
          pb[mt] = *(const short8*)&Ps[pbuf][(mt * 16 + ln) * PSTR + ks * 32 + quad * 8];
#pragma unroll
        for (int ct = 0; ct < 8; ++ct)
#pragma unroll
          for (int mt = 0; mt < 2; ++mt)
            acc[ct][mt] = MFMA16(va[ct][ks], pb[mt], acc[ct][mt]);
      }

      const int j0 = it * JT;
#pragma unroll
      for (int ct = 0; ct < 8; ++ct)
#pragma unroll
        for (int ks = 0; ks < 2; ++ks)
          va[ct][ks] = *(const short8*)(v_base +
              (size_t)(c0 + ct * 16 + ln) * NN + j0 + ks * 32 + quad * 8);
      __syncthreads();   // barrier #(it+1)
    }

    // final PV for tile NIT-1
    {
      const int pbuf = (NIT - 1) & 1;
      float av[2];
#pragma unroll
      for (int mt = 0; mt < 2; ++mt) av[mt] = arow[pbuf][mt * 16 + ln];
#pragma unroll
      for (int ct = 0; ct < 8; ++ct)
#pragma unroll
        for (int mt = 0; mt < 2; ++mt) acc[ct][mt] *= av[mt];
#pragma unroll
      for (int ks = 0; ks < 2; ++ks) {
        short8 pb[2];
#pragma unroll
        for (int mt = 0; mt < 2; ++mt)
          pb[mt] = *(const short8*)&Ps[pbuf][(mt * 16 + ln) * PSTR + ks * 32 + quad * 8];
#pragma unroll
        for (int ct = 0; ct < 8; ++ct)
#pragma unroll
          for (int mt = 0; mt < 2; ++mt)
            acc[ct][mt] = MFMA16(va[ct][ks], pb[mt], acc[ct][mt]);
      }
    }
    __syncthreads();     // barrier #(NIT+1): lrow visible

    // epilogue: out[b][c][m] = gamma*(O'/l) + x
    const float g0 = gamma[0];
    float li[2];
#pragma unroll
    for (int mt = 0; mt < 2; ++mt) li[mt] = 1.f / lrow[mt * 16 + ln];
#pragma unroll
    for (int ct = 0; ct < 8; ++ct)
#pragma unroll
      for (int r = 0; r < 4; ++r) {
        const int c = c0 + ct * 16 + quad * 4 + r;
        const float* xr = x + ((size_t)b * NC + c) * NN + m0;
        float* orow = out + ((size_t)b * NC + c) * NN + m0;
#pragma unroll
        for (int mt = 0; mt < 2; ++mt) {
          const int m = mt * 16 + ln;
          orow[m] = g0 * (acc[ct][mt][r] * li[mt]) + xr[m];
        }
      }
  }
}

extern "C" void kernel_launch(void* const* d_in, const int* in_sizes, int n_in,
                              void* d_out, int out_size, void* d_ws, size_t ws_size,
                              hipStream_t stream) {
  const float* x     = (const float*)d_in[0];
  const float* Wq    = (const float*)d_in[1];
  const float* bq    = (const float*)d_in[2];
  const float* Wk    = (const float*)d_in[3];
  const float* bk    = (const float*)d_in[4];
  const float* Wv    = (const float*)d_in[5];
  const float* bv    = (const float*)d_in[6];
  const float* gamma = (const float*)d_in[7];
  float* out = (float*)d_out;

  __hip_bfloat16* q  = (__hip_bfloat16*)d_ws;               // [B][N][32]  1 MB
  __hip_bfloat16* kT = q  + (size_t)NB * NN * DQK;          // [B][N][32]  1 MB
  __hip_bfloat16* v  = kT + (size_t)NB * NN * DQK;          // [B][C][N]   8.4 MB

  proj_qk_kernel<<<dim3(NN / 64, NB), dim3(256), 0, stream>>>(x, Wq, bq, Wk, bk, q, kT);
  proj_v_kernel<<<dim3(NN / 64, 2, NB), dim3(256), 0, stream>>>(x, Wv, bv, v);
  flash_kernel<<<dim3(NB * NN / MT), dim3(256), 0, stream>>>(q, kT, v, x, gamma, out);
}

// Round 8
// 235.887 us; speedup vs baseline: 1.3714x; 1.3714x over previous
//
#include <hip/hip_runtime.h>
#include <hip/hip_bf16.h>
#include <cstddef>

#define NB  4
#define NC  256
#define NN  4096
#define DQK 32
#define MT  64      // query rows per flash block
#define JT  128     // key tile per iteration (fat tiles -> half the barriers)
#define NIT (NN / JT)
#define PSTR 140    // P row stride in bf16 (280 B rows; b128 reads 2-way max)

typedef __attribute__((ext_vector_type(8))) short short8;
typedef __attribute__((ext_vector_type(4))) float f32x4;

#define MFMA16(a, b, c) __builtin_amdgcn_mfma_f32_16x16x32_bf16((a), (b), (c), 0, 0, 0)

__device__ inline unsigned pk2bf(float a, float b) {
  __hip_bfloat162 h = __float22bfloat162_rn(make_float2(a, b));
  unsigned u;
  __builtin_memcpy(&u, &h, 4);
  return u;
}

// ---- q/k proj: 512 thr, wave-halves split c (halved chain, 8-wide MLP) ----
__global__ __launch_bounds__(512) void proj_qk_kernel(
    const float* __restrict__ x, const float* __restrict__ Wq,
    const float* __restrict__ bq, const float* __restrict__ Wk,
    const float* __restrict__ bk, __hip_bfloat16* __restrict__ q,
    __hip_bfloat16* __restrict__ kT) {
  __shared__ float Rs[256 * 17];   // upper-half partials
  const int t = threadIdx.x;
  const int b = blockIdx.y;
  const int n = blockIdx.x * 64 + (t & 63);
  const int w = __builtin_amdgcn_readfirstlane(t >> 6);   // 0..7
  const int g = w & 3;                    // 0,1: q ; 2,3: k
  const int ch = w >> 2;                  // c-half
  const float* W    = (g < 2) ? Wq : Wk;
  const int obase = (g & 1) * 16;

  float acc[16];
#pragma unroll
  for (int i = 0; i < 16; ++i) acc[i] = 0.f;

  const float* xp = x + ((size_t)b * NC + ch * 128) * NN + n;
  const float* Wp = W + obase * NC + ch * 128;

  float xv[8];
#pragma unroll
  for (int i = 0; i < 8; ++i) xv[i] = xp[(size_t)i * NN];
  for (int cc = 0; cc < 128; cc += 8) {
    float xn[8];
    if (cc + 8 < 128) {
#pragma unroll
      for (int i = 0; i < 8; ++i) xn[i] = xp[(size_t)(cc + 8 + i) * NN];
    }
#pragma unroll
    for (int i = 0; i < 8; ++i)
#pragma unroll
      for (int o = 0; o < 16; ++o) acc[o] += Wp[o * NC + cc + i] * xv[i];
#pragma unroll
    for (int i = 0; i < 8; ++i) xv[i] = xn[i];
  }

  if (w >= 4) {
    const int tl = t - 256;
#pragma unroll
    for (int i = 0; i < 16; ++i) Rs[tl * 17 + i] = acc[i];
  }
  __syncthreads();
  if (w < 4) {
    const float* bias = (g < 2) ? bq : bk;
#pragma unroll
    for (int i = 0; i < 16; ++i) acc[i] += Rs[t * 17 + i] + bias[obase + i];
    __hip_bfloat16* dst = ((g < 2) ? q : kT) + ((size_t)b * NN + n) * DQK + obase;
    unsigned p[8];
#pragma unroll
    for (int i = 0; i < 8; ++i) p[i] = pk2bf(acc[2 * i], acc[2 * i + 1]);
    ((uint4*)dst)[0] = make_uint4(p[0], p[1], p[2], p[3]);
    ((uint4*)dst)[1] = make_uint4(p[4], p[5], p[6], p[7]);
  }
}

// ---- v proj: same structure, y-split over 4 o-quarters ----
__global__ __launch_bounds__(512) void proj_v_kernel(
    const float* __restrict__ x, const float* __restrict__ Wv,
    const float* __restrict__ bv, __hip_bfloat16* __restrict__ v) {
  __shared__ float Rs[256 * 17];
  const int t = threadIdx.x;
  const int b = blockIdx.z;
  const int n = blockIdx.x * 64 + (t & 63);
  const int w = __builtin_amdgcn_readfirstlane(t >> 6);
  const int g = w & 3;
  const int ch = w >> 2;
  const int obase = blockIdx.y * 64 + g * 16;

  float acc[16];
#pragma unroll
  for (int i = 0; i < 16; ++i) acc[i] = 0.f;

  const float* xp = x + ((size_t)b * NC + ch * 128) * NN + n;
  const float* Wp = Wv + obase * NC + ch * 128;

  float xv[8];
#pragma unroll
  for (int i = 0; i < 8; ++i) xv[i] = xp[(size_t)i * NN];
  for (int cc = 0; cc < 128; cc += 8) {
    float xn[8];
    if (cc + 8 < 128) {
#pragma unroll
      for (int i = 0; i < 8; ++i) xn[i] = xp[(size_t)(cc + 8 + i) * NN];
    }
#pragma unroll
    for (int i = 0; i < 8; ++i)
#pragma unroll
      for (int o = 0; o < 16; ++o) acc[o] += Wp[o * NC + cc + i] * xv[i];
#pragma unroll
    for (int i = 0; i < 8; ++i) xv[i] = xn[i];
  }

  if (w >= 4) {
    const int tl = t - 256;
#pragma unroll
    for (int i = 0; i < 16; ++i) Rs[tl * 17 + i] = acc[i];
  }
  __syncthreads();
  if (w < 4) {
#pragma unroll
    for (int i = 0; i < 16; ++i) {
      const int c = obase + i;
      v[((size_t)b * NC + c) * NN + n] =
          __hip_bfloat16(acc[i] + Rs[t * 17 + i] + bv[c]);
    }
  }
}

// ---- wave-specialized flash, MT=64, JT=128: waves 0-3 produce (QK+softmax),
// ---- waves 4-7 consume (PV), double-buffered P, 1 barrier/iter, 32 iters.
__global__ __launch_bounds__(512, 2) void flash_kernel(
    const __hip_bfloat16* __restrict__ q, const __hip_bfloat16* __restrict__ kt,
    const __hip_bfloat16* __restrict__ v, const float* __restrict__ x,
    const float* __restrict__ gamma, float* __restrict__ out) {
  __shared__ __hip_bfloat16 Ps[2][MT * PSTR];   // 35840 B
  __shared__ float arow[2][MT];
  __shared__ float lrow[MT];

  const int t  = threadIdx.x;
  const int bi = blockIdx.x;
  // XCD swizzle: XCD pair {2b,2b+1} serves batch b -> V slice ~2 MB in L2
  const int b  = (bi & 7) >> 1;
  const int m0 = (((bi & 1) * 32) + (bi >> 3)) * MT;

  const int w    = __builtin_amdgcn_readfirstlane(t >> 6);   // 0..7
  const int ln   = t & 15;
  const int quad = (t & 63) >> 4;

  const __hip_bfloat16* kb_base = kt + (size_t)b * NN * DQK;
  const __hip_bfloat16* v_base  = v + (size_t)b * NC * NN;

  if (w < 4) {
    // ---------------- producer: rows [m0+w*16, m0+w*16+16) ----------------
    const short8 qa =
        *(const short8*)(q + ((size_t)b * NN + m0 + w * 16 + ln) * DQK + quad * 8);
    float mreg[4], lreg[4];
#pragma unroll
    for (int r = 0; r < 4; ++r) { mreg[r] = -3.0e38f; lreg[r] = 0.f; }

    f32x4 zero4 = {0.f, 0.f, 0.f, 0.f};
    short8 kb[8];
#pragma unroll
    for (int jt = 0; jt < 8; ++jt)
      kb[jt] = *(const short8*)(kb_base + (size_t)(jt * 16 + ln) * DQK + quad * 8);

    for (int it = 0; it < NIT; ++it) {
      // S strip: 16 m x 128 j, in registers
      f32x4 sf[8];
#pragma unroll
      for (int jt = 0; jt < 8; ++jt) sf[jt] = MFMA16(qa, kb[jt], zero4);

      // prefetch next K straight into kb (dead after the MFMAs above)
      if (it + 1 < NIT) {
        const int jn = (it + 1) * JT;
#pragma unroll
        for (int jt = 0; jt < 8; ++jt)
          kb[jt] = *(const short8*)(kb_base + (size_t)(jn + jt * 16 + ln) * DQK + quad * 8);
      }

      // wave-local online softmax (rows quad*4+r, cols jt*16+ln)
      float rmax[4];
#pragma unroll
      for (int r = 0; r < 4; ++r) {
        float a0 = fmaxf(fmaxf(sf[0][r], sf[1][r]), fmaxf(sf[2][r], sf[3][r]));
        float a1 = fmaxf(fmaxf(sf[4][r], sf[5][r]), fmaxf(sf[6][r], sf[7][r]));
        rmax[r] = fmaxf(a0, a1);
      }
#pragma unroll
      for (int off = 1; off < 16; off <<= 1)
#pragma unroll
        for (int r = 0; r < 4; ++r)
          rmax[r] = fmaxf(rmax[r], __shfl_xor(rmax[r], off));
      float alpha[4];
#pragma unroll
      for (int r = 0; r < 4; ++r) {
        const float mn = fmaxf(mreg[r], rmax[r]);
        alpha[r] = __expf(mreg[r] - mn);
        mreg[r] = mn;
      }
      float e[8][4], rsum[4];
#pragma unroll
      for (int r = 0; r < 4; ++r) rsum[r] = 0.f;
#pragma unroll
      for (int jt = 0; jt < 8; ++jt)
#pragma unroll
        for (int r = 0; r < 4; ++r) {
          e[jt][r] = __expf(sf[jt][r] - mreg[r]);
          rsum[r] += e[jt][r];
        }
#pragma unroll
      for (int off = 1; off < 16; off <<= 1)
#pragma unroll
        for (int r = 0; r < 4; ++r) rsum[r] += __shfl_xor(rsum[r], off);
#pragma unroll
      for (int r = 0; r < 4; ++r) lreg[r] = lreg[r] * alpha[r] + rsum[r];

      const int buf = it & 1;
#pragma unroll
      for (int jt = 0; jt < 8; ++jt)
#pragma unroll
        for (int r = 0; r < 4; ++r)
          Ps[buf][(w * 16 + quad * 4 + r) * PSTR + jt * 16 + ln] = __hip_bfloat16(e[jt][r]);
      if (ln == 0) {
#pragma unroll
        for (int r = 0; r < 4; ++r) arow[buf][w * 16 + quad * 4 + r] = alpha[r];
      }
      __syncthreads();   // barrier #(it+1)
    }
    if (ln == 0) {
#pragma unroll
      for (int r = 0; r < 4; ++r) lrow[w * 16 + quad * 4 + r] = lreg[r];
    }
    __syncthreads();     // barrier #(NIT+1)
  } else {
    // -------- consumer: channels [c0, c0+64), one iter behind --------
    const int c0 = (w - 4) * 64;
    f32x4 zero4 = {0.f, 0.f, 0.f, 0.f};
    f32x4 acc[4][4];   // rows c = c0+ct*16+quad*4+r, cols m = mt*16+ln
#pragma unroll
    for (int ct = 0; ct < 4; ++ct)
#pragma unroll
      for (int mt = 0; mt < 4; ++mt) acc[ct][mt] = zero4;

    // preload V(0): 4 ct-rows x 4 ks-chunks of 32 j
    short8 va[4][4];
#pragma unroll
    for (int ct = 0; ct < 4; ++ct)
#pragma unroll
      for (int ks = 0; ks < 4; ++ks)
        va[ct][ks] = *(const short8*)(v_base +
            (size_t)(c0 + ct * 16 + ln) * NN + ks * 32 + quad * 8);
    __syncthreads();   // barrier #1

    for (int it = 1; it < NIT; ++it) {
      const int pbuf = (it - 1) & 1;
      float av[4];
#pragma unroll
      for (int mt = 0; mt < 4; ++mt) av[mt] = arow[pbuf][mt * 16 + ln];
#pragma unroll
      for (int ct = 0; ct < 4; ++ct)
#pragma unroll
        for (int mt = 0; mt < 4; ++mt) acc[ct][mt] *= av[mt];

      const int j0 = it * JT;
#pragma unroll
      for (int ks = 0; ks < 4; ++ks) {
        short8 pb[4];
#pragma unroll
        for (int mt = 0; mt < 4; ++mt)
          pb[mt] = *(const short8*)&Ps[pbuf][(mt * 16 + ln) * PSTR + ks * 32 + quad * 8];
#pragma unroll
        for (int ct = 0; ct < 4; ++ct)
#pragma unroll
          for (int mt = 0; mt < 4; ++mt)
            acc[ct][mt] = MFMA16(va[ct][ks], pb[mt], acc[ct][mt]);
        // va[*][ks] now dead -> reload for V(it), covered by later MFMAs
#pragma unroll
        for (int ct = 0; ct < 4; ++ct)
          va[ct][ks] = *(const short8*)(v_base +
              (size_t)(c0 + ct * 16 + ln) * NN + j0 + ks * 32 + quad * 8);
      }
      __syncthreads();   // barrier #(it+1)
    }

    // final PV for tile NIT-1
    {
      const int pbuf = (NIT - 1) & 1;
      float av[4];
#pragma unroll
      for (int mt = 0; mt < 4; ++mt) av[mt] = arow[pbuf][mt * 16 + ln];
#pragma unroll
      for (int ct = 0; ct < 4; ++ct)
#pragma unroll
        for (int mt = 0; mt < 4; ++mt) acc[ct][mt] *= av[mt];
#pragma unroll
      for (int ks = 0; ks < 4; ++ks) {
        short8 pb[4];
#pragma unroll
        for (int mt = 0; mt < 4; ++mt)
          pb[mt] = *(const short8*)&Ps[pbuf][(mt * 16 + ln) * PSTR + ks * 32 + quad * 8];
#pragma unroll
        for (int ct = 0; ct < 4; ++ct)
#pragma unroll
          for (int mt = 0; mt < 4; ++mt)
            acc[ct][mt] = MFMA16(va[ct][ks], pb[mt], acc[ct][mt]);
      }
    }
    __syncthreads();     // barrier #(NIT+1): lrow visible

    // epilogue: out[b][c][m] = gamma*(O'/l) + x
    const float g0 = gamma[0];
    float li[4];
#pragma unroll
    for (int mt = 0; mt < 4; ++mt) li[mt] = 1.f / lrow[mt * 16 + ln];
#pragma unroll
    for (int ct = 0; ct < 4; ++ct)
#pragma unroll
      for (int r = 0; r < 4; ++r) {
        const int c = c0 + ct * 16 + quad * 4 + r;
        const float* xr = x + ((size_t)b * NC + c) * NN + m0;
        float* orow = out + ((size_t)b * NC + c) * NN + m0;
#pragma unroll
        for (int mt = 0; mt < 4; ++mt) {
          const int m = mt * 16 + ln;
          orow[m] = g0 * (acc[ct][mt][r] * li[mt]) + xr[m];
        }
      }
  }
}

extern "C" void kernel_launch(void* const* d_in, const int* in_sizes, int n_in,
                              void* d_out, int out_size, void* d_ws, size_t ws_size,
                              hipStream_t stream) {
  const float* x     = (const float*)d_in[0];
  const float* Wq    = (const float*)d_in[1];
  const float* bq    = (const float*)d_in[2];
  const float* Wk    = (const float*)d_in[3];
  const float* bk    = (const float*)d_in[4];
  const float* Wv    = (const float*)d_in[5];
  const float* bv    = (const float*)d_in[6];
  const float* gamma = (const float*)d_in[7];
  float* out = (float*)d_out;

  __hip_bfloat16* q  = (__hip_bfloat16*)d_ws;               // [B][N][32]  1 MB
  __hip_bfloat16* kT = q  + (size_t)NB * NN * DQK;          // [B][N][32]  1 MB
  __hip_bfloat16* v  = kT + (size_t)NB * NN * DQK;          // [B][C][N]   8.4 MB

  proj_qk_kernel<<<dim3(NN / 64, NB), dim3(512), 0, stream>>>(x, Wq, bq, Wk, bk, q, kT);
  proj_v_kernel<<<dim3(NN / 64, 4, NB), dim3(512), 0, stream>>>(x, Wv, bv, v);
  flash_kernel<<<dim3(NB * NN / MT), dim3(512), 0, stream>>>(q, kT, v, x, gamma, out);
}